// Round 10
// baseline (10035.972 us; speedup 1.0000x reference)
//
#include <hip/hip_runtime.h>
#include <cstdint>
#include <cstddef>

#define T_STEPS 2048
#define BATCH   16
#define NIN_D   1024
#define NH_D    1024
#define G_D     4096
#define MROWS   32768   // T*B
#define NWG     64      // scan workgroups
#define WGT     512     // threads per scan wg (8 waves)
#define PWORDS  8192    // packed u32 words per step buffer (2 bf16 each = 32 KB)

typedef short short8 __attribute__((ext_vector_type(8)));
typedef float f32x4  __attribute__((ext_vector_type(4)));
typedef unsigned u32x4 __attribute__((ext_vector_type(4)));

__device__ __forceinline__ unsigned short f2bf(float f) {
  unsigned u = __builtin_bit_cast(unsigned, f);
  u += 0x7FFFu + ((u >> 16) & 1u);          // RNE
  return (unsigned short)(u >> 16);
}
__device__ __forceinline__ float bf2f(unsigned short h) {
  unsigned u = ((unsigned)h) << 16;
  return __builtin_bit_cast(float, u);
}
__device__ __forceinline__ float sigmoidf_(float x) { return 1.0f / (1.0f + __expf(-x)); }
__device__ __forceinline__ float tanhf_(float x)    { return 2.0f / (1.0f + __expf(-2.0f * x)) - 1.0f; }

// ---------------- cast X: f32 -> bf16, vectorized ----------------
__global__ void cast_f32_bf16(const float* __restrict__ in, unsigned short* __restrict__ out, int n4) {
  int idx = blockIdx.x * blockDim.x + threadIdx.x;
  if (idx < n4) {
    float4 v = ((const float4*)in)[idx];
    ushort4 o;
    o.x = f2bf(v.x); o.y = f2bf(v.y); o.z = f2bf(v.z); o.w = f2bf(v.w);
    ((ushort4*)out)[idx] = o;
  }
}

// ---------------- transpose+cast W [1024][4096] f32 -> WT [4096][1024] bf16 ----------------
__global__ void transpose_cast(const float* __restrict__ in, unsigned short* __restrict__ out) {
  __shared__ float tile[32][33];
  const int gx = blockIdx.x * 32;
  const int gy = blockIdx.y * 32;
  const int tx = threadIdx.x, ty = threadIdx.y;   // (32,8)
  #pragma unroll
  for (int p = 0; p < 4; ++p)
    tile[ty + p * 8][tx] = in[(size_t)(gy + ty + p * 8) * G_D + gx + tx];
  __syncthreads();
  #pragma unroll
  for (int p = 0; p < 4; ++p)
    out[(size_t)(gx + ty + p * 8) * NIN_D + gy + tx] = f2bf(tile[tx][ty + p * 8]);
}

// ---------------- init h sequence: buf0 = packed bf16(h0); bufs 1..2047 = 0xFFFFFFFF ----------------
// Empty-encoding: half-word 0xFFFF (-NaN bf16) is never produced by f2bf of LSTM
// outputs (|y| < 1), so "any half == 0xFFFF" <=> word not yet written.
// Runs every launch -> resets protocol state between graph replays (determinism).
__global__ void init_hseq(const float* __restrict__ h0, u32x4* __restrict__ hs) {
  const int nq = (T_STEPS * PWORDS) / 4;   // 4,194,304 quads (64 MB)
  for (int q = blockIdx.x * blockDim.x + threadIdx.x; q < nq; q += gridDim.x * blockDim.x) {
    u32x4 v;
    if (q < PWORDS / 4) {
      #pragma unroll
      for (int u = 0; u < 4; ++u) {
        unsigned lo = f2bf(h0[8 * q + 2 * u]);
        unsigned hi = f2bf(h0[8 * q + 2 * u + 1]);
        lo = (lo == 0xFFFFu) ? 0xFFFEu : lo;   // robustness: never poison
        hi = (hi == 0xFFFFu) ? 0xFFFEu : hi;
        v[u] = lo | (hi << 16);
      }
    } else {
      v = (u32x4){0xFFFFFFFFu, 0xFFFFFFFFu, 0xFFFFFFFFu, 0xFFFFFFFFu};
    }
    hs[q] = v;
  }
}

// ---------------- intern GEMM: C[m][g] = A[m][:] . BT[g][:] + bias[g] (bf16 out) ----------------
__global__ __launch_bounds__(256) void gemm_intern(
    const unsigned short* __restrict__ A,
    const unsigned short* __restrict__ Bt,
    const float* __restrict__ bias,
    unsigned short* __restrict__ Out) {
  __shared__ unsigned short As[128 * 72];
  __shared__ unsigned short Bs[128 * 72];
  const int tid  = threadIdx.x;
  const int lane = tid & 63;
  const int w    = tid >> 6;
  const int r16  = lane & 15;
  const int kgrp = lane >> 4;
  const int wrow = (w >> 1) * 64;
  const int wcol = (w & 1) * 64;
  const int bx = blockIdx.x;
  const int by = blockIdx.y;

  const unsigned short* Ag = A  + (size_t)by * 128 * NIN_D;
  const unsigned short* Bg = Bt + (size_t)bx * 128 * NIN_D;
  const int trow = tid >> 3;
  const int tcol = (tid & 7) * 8;

  f32x4 acc[4][4];
  #pragma unroll
  for (int m = 0; m < 4; ++m)
    #pragma unroll
    for (int n = 0; n < 4; ++n)
      acc[m][n] = (f32x4){0.f, 0.f, 0.f, 0.f};

  for (int kt = 0; kt < 16; ++kt) {
    const int kb = kt * 64;
    __syncthreads();
    #pragma unroll
    for (int p = 0; p < 4; ++p) {
      const int r = trow + p * 32;
      *(uint4*)(&As[r * 72 + tcol]) = *(const uint4*)(Ag + (size_t)r * NIN_D + kb + tcol);
      *(uint4*)(&Bs[r * 72 + tcol]) = *(const uint4*)(Bg + (size_t)r * NIN_D + kb + tcol);
    }
    __syncthreads();
    #pragma unroll
    for (int kk = 0; kk < 2; ++kk) {
      const int ko = kk * 32 + kgrp * 8;
      short8 af[4], bq[4];
      #pragma unroll
      for (int m = 0; m < 4; ++m)
        af[m] = *(const short8*)(&As[(wrow + m * 16 + r16) * 72 + ko]);
      #pragma unroll
      for (int n = 0; n < 4; ++n)
        bq[n] = *(const short8*)(&Bs[(wcol + n * 16 + r16) * 72 + ko]);
      #pragma unroll
      for (int m = 0; m < 4; ++m)
        #pragma unroll
        for (int n = 0; n < 4; ++n)
          acc[m][n] = __builtin_amdgcn_mfma_f32_16x16x32_bf16(af[m], bq[n], acc[m][n], 0, 0, 0);
    }
  }
  #pragma unroll
  for (int n = 0; n < 4; ++n) {
    const int col = bx * 128 + wcol + n * 16 + r16;
    const float bv = bias[col];
    #pragma unroll
    for (int m = 0; m < 4; ++m) {
      const int row0 = by * 128 + wrow + m * 16 + kgrp * 4;
      #pragma unroll
      for (int i = 0; i < 4; ++i)
        Out[(size_t)(row0 + i) * G_D + col] = f2bf(acc[m][n][i] + bv);
    }
  }
}

// issue this lane's 8 A-fragment dwordx4 loads (L1/L2-bypassing); offsets kc*64B
#define POLL8(P) asm volatile( \
    "global_load_dwordx4 %0, %8, off sc0 sc1\n\t" \
    "global_load_dwordx4 %1, %8, off offset:64 sc0 sc1\n\t" \
    "global_load_dwordx4 %2, %8, off offset:128 sc0 sc1\n\t" \
    "global_load_dwordx4 %3, %8, off offset:192 sc0 sc1\n\t" \
    "global_load_dwordx4 %4, %8, off offset:256 sc0 sc1\n\t" \
    "global_load_dwordx4 %5, %8, off offset:320 sc0 sc1\n\t" \
    "global_load_dwordx4 %6, %8, off offset:384 sc0 sc1\n\t" \
    "global_load_dwordx4 %7, %8, off offset:448 sc0 sc1" \
    : "=v"(q0), "=v"(q1), "=v"(q2), "=v"(q3), \
      "=v"(q4), "=v"(q5), "=v"(q6), "=v"(q7) \
    : "v"(P) : "memory")

__device__ __forceinline__ bool fresh4_(u32x4 v) {
  bool ok = true;
  #pragma unroll
  for (int u = 0; u < 4; ++u)
    ok = ok && ((v[u] & 0xFFFFu) != 0xFFFFu) && ((v[u] >> 16) != 0xFFFFu);
  return ok;
}

// ---------------- persistent LSTM scan ----------------
// 64 wgs x 512 threads (8 waves). wg owns 16 hidden units = 64 gate cols.
// Wave wv = (ks<<1)|gp: K-quarter ks, gate-pair gp. Lane (r16,kgrp) polls EXACTLY
// its MFMA A-fragment words of the per-step fresh buffer (accepting load == payload,
// bit_cast to short8 -- no LDS for h, no unpack, no pre-MFMA barrier). z partials
// go through parity-double-buffered z_s; ONE __syncthreads per step.
__global__ __launch_bounds__(WGT, 2) void lstm_scan(
    const unsigned short* __restrict__ intern, // [32768][4096] bf16
    const unsigned short* __restrict__ WreT,   // [4096][1024] bf16
    const float* __restrict__ msk,             // [2048][16]
    const float* __restrict__ c0,              // [16][1024]
    unsigned* __restrict__ hseq,               // [2048][PWORDS] packed 2xbf16
    float* __restrict__ Y, float* __restrict__ C, float* __restrict__ D) {
  const int wg = blockIdx.x;
  const int tid = threadIdx.x;
  const int wv = tid >> 6, lane = tid & 63;
  const int r16 = lane & 15, kgrp = lane >> 4;
  const int ks = wv >> 1, gp = wv & 1;
  const int j0 = wg * 16;

  __shared__ __attribute__((aligned(16))) float z_s[2][4][4][16][20];  // [par][ks][gate][j][b+pad]

  // ---- W_re B-fragments (gates 2gp,2gp+1; cols j0..j0+15; K-quarter ks) ----
  short8 wfrag[2][8];
  #pragma unroll
  for (int g2 = 0; g2 < 2; ++g2) {
    const unsigned short* wp =
        WreT + (size_t)((2 * gp + g2) * NH_D + j0 + r16) * NH_D + ks * 256 + kgrp * 8;
    #pragma unroll
    for (int kc = 0; kc < 8; ++kc)
      wfrag[g2][kc] = *(const short8*)(wp + kc * 32);
  }

  // ---- gate-thread mapping: tid<256 (waves 0..3) -> (b = tid>>4, jj = tid&15) ----
  const int b = tid >> 4, jj = tid & 15;
  const bool gt = tid < 256;
  float creg = 0.f, mreg = 0.f;
  unsigned short ipr[4] = {0, 0, 0, 0};
  if (gt) {
    creg = c0[b * NH_D + j0 + jj];
    mreg = msk[b];
    #pragma unroll
    for (int g = 0; g < 4; ++g)
      ipr[g] = intern[(size_t)b * G_D + g * NH_D + j0 + jj];
  }

  // per-lane poll base: packed words of h[b=r16][k = ks*256 + kc*32 + kgrp*8 .. +8]
  const int poffw = r16 * 512 + ks * 128 + kgrp * 4;   // u32 word offset

  u32x4 q0, q1, q2, q3, q4, q5, q6, q7;
  POLL8(hseq + poffw);   // buffer 0 (pre-published by init_hseq)

  for (int t = 0; t < T_STEPS; ++t) {
    const int par = t & 1;
    const unsigned* pb = hseq + (size_t)t * PWORDS + poffw;

    // ---- wait + accept: all 32 packed words fresh (no 0xFFFF half) ----
    for (;;) {
      asm volatile("s_waitcnt vmcnt(0)" ::: "memory");
      __builtin_amdgcn_sched_barrier(0);
      bool ok = fresh4_(q0) && fresh4_(q1) && fresh4_(q2) && fresh4_(q3)
             && fresh4_(q4) && fresh4_(q5) && fresh4_(q6) && fresh4_(q7);
      if (__all((int)ok)) break;
      POLL8(pb);   // re-issue; RT is the natural pacing
    }

    // ---- payloads ARE the A-fragments ----
    short8 a0 = __builtin_bit_cast(short8, q0), a1 = __builtin_bit_cast(short8, q1);
    short8 a2 = __builtin_bit_cast(short8, q2), a3 = __builtin_bit_cast(short8, q3);
    short8 a4 = __builtin_bit_cast(short8, q4), a5 = __builtin_bit_cast(short8, q5);
    short8 a6 = __builtin_bit_cast(short8, q6), a7 = __builtin_bit_cast(short8, q7);

    // ---- MFMA: 2 gates x (16x16, K=256) ----
    f32x4 acc0 = (f32x4){0.f, 0.f, 0.f, 0.f};
    f32x4 acc1 = (f32x4){0.f, 0.f, 0.f, 0.f};
    acc0 = __builtin_amdgcn_mfma_f32_16x16x32_bf16(a0, wfrag[0][0], acc0, 0, 0, 0);
    acc1 = __builtin_amdgcn_mfma_f32_16x16x32_bf16(a0, wfrag[1][0], acc1, 0, 0, 0);
    acc0 = __builtin_amdgcn_mfma_f32_16x16x32_bf16(a1, wfrag[0][1], acc0, 0, 0, 0);
    acc1 = __builtin_amdgcn_mfma_f32_16x16x32_bf16(a1, wfrag[1][1], acc1, 0, 0, 0);
    acc0 = __builtin_amdgcn_mfma_f32_16x16x32_bf16(a2, wfrag[0][2], acc0, 0, 0, 0);
    acc1 = __builtin_amdgcn_mfma_f32_16x16x32_bf16(a2, wfrag[1][2], acc1, 0, 0, 0);
    acc0 = __builtin_amdgcn_mfma_f32_16x16x32_bf16(a3, wfrag[0][3], acc0, 0, 0, 0);
    acc1 = __builtin_amdgcn_mfma_f32_16x16x32_bf16(a3, wfrag[1][3], acc1, 0, 0, 0);
    acc0 = __builtin_amdgcn_mfma_f32_16x16x32_bf16(a4, wfrag[0][4], acc0, 0, 0, 0);
    acc1 = __builtin_amdgcn_mfma_f32_16x16x32_bf16(a4, wfrag[1][4], acc1, 0, 0, 0);
    acc0 = __builtin_amdgcn_mfma_f32_16x16x32_bf16(a5, wfrag[0][5], acc0, 0, 0, 0);
    acc1 = __builtin_amdgcn_mfma_f32_16x16x32_bf16(a5, wfrag[1][5], acc1, 0, 0, 0);
    acc0 = __builtin_amdgcn_mfma_f32_16x16x32_bf16(a6, wfrag[0][6], acc0, 0, 0, 0);
    acc1 = __builtin_amdgcn_mfma_f32_16x16x32_bf16(a6, wfrag[1][6], acc1, 0, 0, 0);
    acc0 = __builtin_amdgcn_mfma_f32_16x16x32_bf16(a7, wfrag[0][7], acc0, 0, 0, 0);
    acc1 = __builtin_amdgcn_mfma_f32_16x16x32_bf16(a7, wfrag[1][7], acc1, 0, 0, 0);

    // C-frag: col(j)=r16, row(b)=kgrp*4+i -> b128 store into parity z_s
    *(f32x4*)&z_s[par][ks][2 * gp + 0][r16][kgrp * 4] = acc0;
    *(f32x4*)&z_s[par][ks][2 * gp + 1][r16][kgrp * 4] = acc1;
    __syncthreads();   // B1: the ONLY barrier per step

    if (gt) {
      // ---- gates (thread = (b, jj)): sum the 4 K-quarter partials ----
      float zq[4];
      #pragma unroll
      for (int g = 0; g < 4; ++g)
        zq[g] = ((z_s[par][0][g][jj][b] + z_s[par][1][g][jj][b]) +
                 (z_s[par][2][g][jj][b] + z_s[par][3][g][jj][b])) + bf2f(ipr[g]);
      const float cell = tanhf_(zq[0]);
      const float ig = sigmoidf_(zq[1]);
      const float fg = sigmoidf_(zq[2]);
      const float og = sigmoidf_(zq[3]);
      const float cn = fg * creg + ig * cell;
      const float yn = og * tanhf_(cn);
      const float cnew = mreg * cn + (1.0f - mreg) * creg;
      const float ynew = mreg * yn;
      creg = cnew;

      // ---- publish h(t+1) into the FRESH buffer t+1 (critical path) ----
      if (t < T_STEPS - 1) {
        const unsigned short yb = f2bf(ynew);
        const unsigned prt = (unsigned)(unsigned short)__shfl_xor((int)(unsigned)yb, 1);
        if ((tid & 1) == 0) {
          unsigned* dst = hseq + (size_t)(t + 1) * PWORDS;
          __hip_atomic_store(&dst[b * 512 + ((j0 + jj) >> 1)],
                             ((unsigned)yb) | (prt << 16),
                             __ATOMIC_RELAXED, __HIP_MEMORY_SCOPE_AGENT);
        }
      }
      // outputs + next-step operand prefetch (off critical path, after poll issue below? 
      // issue order: publish done; poll issued next stmt outside gt-block for uniformity)
      const size_t ob = ((size_t)t * BATCH + b) * NH_D + j0 + jj;
      __builtin_nontemporal_store(ynew, &Y[ob]);
      __builtin_nontemporal_store(cnew, &C[ob]);
      if (t < T_STEPS - 1) {
        const unsigned short* ipn = intern + ((size_t)(t + 1) * BATCH + b) * G_D;
        #pragma unroll
        for (int g = 0; g < 4; ++g)
          ipr[g] = ipn[g * NH_D + j0 + jj];
        mreg = msk[(t + 1) * BATCH + b];
      }
    }

    // non-gate waves reach this right after B1 -> their poll overlaps the gate phase
    if (t < T_STEPS - 1)
      POLL8(hseq + (size_t)(t + 1) * PWORDS + poffw);
  }
  if (gt) D[b * NH_D + j0 + jj] = creg;
}

extern "C" void kernel_launch(void* const* d_in, const int* in_sizes, int n_in,
                              void* d_out, int out_size, void* d_ws, size_t ws_size,
                              hipStream_t stream) {
  const float* X     = (const float*)d_in[0];
  const float* imask = (const float*)d_in[1];
  const float* h0    = (const float*)d_in[2];
  const float* c0    = (const float*)d_in[3];
  const float* Win   = (const float*)d_in[4];
  const float* Wre   = (const float*)d_in[5];
  const float* bias  = (const float*)d_in[6];
  float* out = (float*)d_out;

  char* ws = (char*)d_ws;
  unsigned short* Xbf    = (unsigned short*)(ws);                         // 64 MB (dead after gemm)
  unsigned short* WinT   = (unsigned short*)(ws + 67108864);              // 8 MB
  unsigned short* WreT   = (unsigned short*)(ws + 75497472);              // 8 MB
  unsigned short* intern = (unsigned short*)(ws + 83886080);              // 256 MB
  unsigned*       hseq   = (unsigned*)(ws);                               // 64 MB = 2048 x 32 KB, overlays Xbf

  float* Y = out;
  float* C = out + (size_t)T_STEPS * BATCH * NH_D;
  float* D = out + (size_t)2 * T_STEPS * BATCH * NH_D;

  {
    int n4 = (MROWS * NIN_D) / 4;
    cast_f32_bf16<<<dim3((n4 + 255) / 256), dim3(256), 0, stream>>>(X, Xbf, n4);
  }
  transpose_cast<<<dim3(G_D / 32, NIN_D / 32), dim3(32, 8), 0, stream>>>(Win, WinT);
  transpose_cast<<<dim3(G_D / 32, NH_D / 32),  dim3(32, 8), 0, stream>>>(Wre, WreT);

  gemm_intern<<<dim3(G_D / 128, MROWS / 128), dim3(256), 0, stream>>>(Xbf, WinT, bias, intern);

  // hseq overlays the (now dead) Xbf region; fill buf0 = h0, rest = empty, every launch
  init_hseq<<<dim3(1024), dim3(256), 0, stream>>>(h0, (u32x4*)hseq);

  lstm_scan<<<dim3(NWG), dim3(WGT), 0, stream>>>(intern, WreT, imask, c0, hseq, Y, C, D);
}

// Round 11
// 7117.557 us; speedup vs baseline: 1.4100x; 1.4100x over previous
//
#include <hip/hip_runtime.h>
#include <cstdint>
#include <cstddef>

#define T_STEPS 2048
#define BATCH   16
#define NIN_D   1024
#define NH_D    1024
#define G_D     4096
#define MROWS   32768   // T*B
#define NWG     64      // scan workgroups
#define WGT     512     // threads per scan wg (8 waves)
#define PWORDS  8192    // packed u32 words per step buffer (2 bf16 each = 32 KB)

typedef short short8 __attribute__((ext_vector_type(8)));
typedef float f32x4  __attribute__((ext_vector_type(4)));
typedef unsigned u32x4 __attribute__((ext_vector_type(4)));

__device__ __forceinline__ unsigned short f2bf(float f) {
  unsigned u = __builtin_bit_cast(unsigned, f);
  u += 0x7FFFu + ((u >> 16) & 1u);          // RNE
  return (unsigned short)(u >> 16);
}
__device__ __forceinline__ float bf2f(unsigned short h) {
  unsigned u = ((unsigned)h) << 16;
  return __builtin_bit_cast(float, u);
}
__device__ __forceinline__ float sigmoidf_(float x) { return 1.0f / (1.0f + __expf(-x)); }
__device__ __forceinline__ float tanhf_(float x)    { return 2.0f / (1.0f + __expf(-2.0f * x)) - 1.0f; }

// ---------------- cast X: f32 -> bf16, vectorized ----------------
__global__ void cast_f32_bf16(const float* __restrict__ in, unsigned short* __restrict__ out, int n4) {
  int idx = blockIdx.x * blockDim.x + threadIdx.x;
  if (idx < n4) {
    float4 v = ((const float4*)in)[idx];
    ushort4 o;
    o.x = f2bf(v.x); o.y = f2bf(v.y); o.z = f2bf(v.z); o.w = f2bf(v.w);
    ((ushort4*)out)[idx] = o;
  }
}

// ---------------- transpose+cast W [1024][4096] f32 -> WT [4096][1024] bf16 ----------------
__global__ void transpose_cast(const float* __restrict__ in, unsigned short* __restrict__ out) {
  __shared__ float tile[32][33];
  const int gx = blockIdx.x * 32;
  const int gy = blockIdx.y * 32;
  const int tx = threadIdx.x, ty = threadIdx.y;   // (32,8)
  #pragma unroll
  for (int p = 0; p < 4; ++p)
    tile[ty + p * 8][tx] = in[(size_t)(gy + ty + p * 8) * G_D + gx + tx];
  __syncthreads();
  #pragma unroll
  for (int p = 0; p < 4; ++p)
    out[(size_t)(gx + ty + p * 8) * NIN_D + gy + tx] = f2bf(tile[tx][ty + p * 8]);
}

// ---------------- init h sequence (FRAGMENT-LINEAR layout) ----------------
// Buffer layout: word w -> chunk c=w>>6, b=(w&63)>>2, k = c*8 + (w&3)*2  (pair k,k+1).
// buf0 = packed bf16(h0); bufs 1..2047 = 0xFFFFFFFF (empty; 0xFFFF half never
// produced by f2bf of LSTM outputs, |y| <= 1). Runs every launch (replay-safe).
__global__ void init_hseq(const float* __restrict__ h0, u32x4* __restrict__ hs) {
  const int nq = (T_STEPS * PWORDS) / 4;   // 4,194,304 quads (64 MB)
  for (int q = blockIdx.x * blockDim.x + threadIdx.x; q < nq; q += gridDim.x * blockDim.x) {
    u32x4 v;
    if (q < PWORDS / 4) {
      const int c = q >> 4, b = q & 15;          // quad = (chunk c, row b), 4 k-pairs
      const float* hb = h0 + b * NH_D + c * 8;
      #pragma unroll
      for (int u = 0; u < 4; ++u) {
        unsigned lo = f2bf(hb[2 * u]);
        unsigned hi = f2bf(hb[2 * u + 1]);
        lo = (lo == 0xFFFFu) ? 0xFFFEu : lo;     // robustness: never poison
        hi = (hi == 0xFFFFu) ? 0xFFFEu : hi;
        v[u] = lo | (hi << 16);
      }
    } else {
      v = (u32x4){0xFFFFFFFFu, 0xFFFFFFFFu, 0xFFFFFFFFu, 0xFFFFFFFFu};
    }
    hs[q] = v;
  }
}

// ---------------- intern GEMM: C[m][g] = A[m][:] . BT[g][:] + bias[g] (bf16 out) ----------------
__global__ __launch_bounds__(256) void gemm_intern(
    const unsigned short* __restrict__ A,
    const unsigned short* __restrict__ Bt,
    const float* __restrict__ bias,
    unsigned short* __restrict__ Out) {
  __shared__ unsigned short As[128 * 72];
  __shared__ unsigned short Bs[128 * 72];
  const int tid  = threadIdx.x;
  const int lane = tid & 63;
  const int w    = tid >> 6;
  const int r16  = lane & 15;
  const int kgrp = lane >> 4;
  const int wrow = (w >> 1) * 64;
  const int wcol = (w & 1) * 64;
  const int bx = blockIdx.x;
  const int by = blockIdx.y;

  const unsigned short* Ag = A  + (size_t)by * 128 * NIN_D;
  const unsigned short* Bg = Bt + (size_t)bx * 128 * NIN_D;
  const int trow = tid >> 3;
  const int tcol = (tid & 7) * 8;

  f32x4 acc[4][4];
  #pragma unroll
  for (int m = 0; m < 4; ++m)
    #pragma unroll
    for (int n = 0; n < 4; ++n)
      acc[m][n] = (f32x4){0.f, 0.f, 0.f, 0.f};

  for (int kt = 0; kt < 16; ++kt) {
    const int kb = kt * 64;
    __syncthreads();
    #pragma unroll
    for (int p = 0; p < 4; ++p) {
      const int r = trow + p * 32;
      *(uint4*)(&As[r * 72 + tcol]) = *(const uint4*)(Ag + (size_t)r * NIN_D + kb + tcol);
      *(uint4*)(&Bs[r * 72 + tcol]) = *(const uint4*)(Bg + (size_t)r * NIN_D + kb + tcol);
    }
    __syncthreads();
    #pragma unroll
    for (int kk = 0; kk < 2; ++kk) {
      const int ko = kk * 32 + kgrp * 8;
      short8 af[4], bq[4];
      #pragma unroll
      for (int m = 0; m < 4; ++m)
        af[m] = *(const short8*)(&As[(wrow + m * 16 + r16) * 72 + ko]);
      #pragma unroll
      for (int n = 0; n < 4; ++n)
        bq[n] = *(const short8*)(&Bs[(wcol + n * 16 + r16) * 72 + ko]);
      #pragma unroll
      for (int m = 0; m < 4; ++m)
        #pragma unroll
        for (int n = 0; n < 4; ++n)
          acc[m][n] = __builtin_amdgcn_mfma_f32_16x16x32_bf16(af[m], bq[n], acc[m][n], 0, 0, 0);
    }
  }
  #pragma unroll
  for (int n = 0; n < 4; ++n) {
    const int col = bx * 128 + wcol + n * 16 + r16;
    const float bv = bias[col];
    #pragma unroll
    for (int m = 0; m < 4; ++m) {
      const int row0 = by * 128 + wrow + m * 16 + kgrp * 4;
      #pragma unroll
      for (int i = 0; i < 4; ++i)
        Out[(size_t)(row0 + i) * G_D + col] = f2bf(acc[m][n][i] + bv);
    }
  }
}

// issue this lane's 8 A-fragment dwordx4 loads. With the fragment-linear layout,
// each wave-level load covers a CONTIGUOUS 1 KB block (perfect coalescing).
// PL/PH are byte pointers 4096B apart; offsets kc*1024.
#define POLL8(PL, PH) asm volatile( \
    "global_load_dwordx4 %0, %8, off sc0 sc1\n\t" \
    "global_load_dwordx4 %1, %8, off offset:1024 sc0 sc1\n\t" \
    "global_load_dwordx4 %2, %8, off offset:2048 sc0 sc1\n\t" \
    "global_load_dwordx4 %3, %8, off offset:3072 sc0 sc1\n\t" \
    "global_load_dwordx4 %4, %9, off sc0 sc1\n\t" \
    "global_load_dwordx4 %5, %9, off offset:1024 sc0 sc1\n\t" \
    "global_load_dwordx4 %6, %9, off offset:2048 sc0 sc1\n\t" \
    "global_load_dwordx4 %7, %9, off offset:3072 sc0 sc1" \
    : "=v"(q0), "=v"(q1), "=v"(q2), "=v"(q3), \
      "=v"(q4), "=v"(q5), "=v"(q6), "=v"(q7) \
    : "v"(PL), "v"(PH) : "memory")

__device__ __forceinline__ bool fresh4_(u32x4 v) {
  bool ok = true;
  #pragma unroll
  for (int u = 0; u < 4; ++u)
    ok = ok && ((v[u] & 0xFFFFu) != 0xFFFFu) && ((v[u] >> 16) != 0xFFFFu);
  return ok;
}

// ---------------- persistent LSTM scan ----------------
// 64 wgs x 512 threads (8 waves). wg owns 16 hidden units = 64 gate cols.
// Wave wv = (ks<<1)|gp: K-quarter ks, gate-pair gp. Lane (r16,kgrp) polls exactly
// its MFMA A-fragment words of the per-step fresh buffer (fragment-linear layout ->
// coalesced 1KB/wave-load; accepting load == payload; bit_cast to short8; no LDS
// for h; no pre-MFMA barrier). z partials via parity-dbuf z_s; ONE barrier/step.
__global__ __launch_bounds__(WGT, 2) void lstm_scan(
    const unsigned short* __restrict__ intern, // [32768][4096] bf16
    const unsigned short* __restrict__ WreT,   // [4096][1024] bf16
    const float* __restrict__ msk,             // [2048][16]
    const float* __restrict__ c0,              // [16][1024]
    unsigned* __restrict__ hseq,               // [2048][PWORDS] fragment-linear packed
    float* __restrict__ Y, float* __restrict__ C, float* __restrict__ D) {
  const int wg = blockIdx.x;
  const int tid = threadIdx.x;
  const int wv = tid >> 6, lane = tid & 63;
  const int r16 = lane & 15, kgrp = lane >> 4;
  const int ks = wv >> 1, gp = wv & 1;
  const int j0 = wg * 16;

  __shared__ __attribute__((aligned(16))) float z_s[2][4][4][16][20];  // [par][ks][gate][j][b+pad]

  // ---- W_re B-fragments (gates 2gp,2gp+1; cols j0..j0+15; K-quarter ks) ----
  short8 wfrag[2][8];
  #pragma unroll
  for (int g2 = 0; g2 < 2; ++g2) {
    const unsigned short* wp =
        WreT + (size_t)((2 * gp + g2) * NH_D + j0 + r16) * NH_D + ks * 256 + kgrp * 8;
    #pragma unroll
    for (int kc = 0; kc < 8; ++kc)
      wfrag[g2][kc] = *(const short8*)(wp + kc * 32);
  }

  // ---- gate-thread mapping: tid<256 (waves 0..3) -> (b = tid>>4, jj = tid&15) ----
  const int b = tid >> 4, jj = tid & 15;
  const bool gt = tid < 256;
  float creg = 0.f, mreg = 0.f;
  unsigned short ipr[4] = {0, 0, 0, 0};
  if (gt) {
    creg = c0[b * NH_D + j0 + jj];
    mreg = msk[b];
    #pragma unroll
    for (int g = 0; g < 4; ++g)
      ipr[g] = intern[(size_t)b * G_D + g * NH_D + j0 + jj];
  }

  // per-lane poll base (bytes): chunk c0 = ks*32 + kgrp, word = c0*64 + r16*4
  const int pboff = ks * 8192 + kgrp * 256 + r16 * 16;
  // producer publish word (pair writer): j = j0 + jj, word = (j>>3)*64 + b*4 + ((j&7)>>1)
  const int pubw = (((j0 + jj) >> 3) << 6) | (b << 2) | (((j0 + jj) & 7) >> 1);

  u32x4 q0, q1, q2, q3, q4, q5, q6, q7;
  {
    const char* pl = (const char*)hseq + pboff;
    POLL8(pl, pl + 4096);   // buffer 0 (pre-published by init_hseq)
  }

  for (int t = 0; t < T_STEPS; ++t) {
    const int par = t & 1;
    const char* pl = (const char*)(hseq + (size_t)t * PWORDS) + pboff;

    // ---- wait + accept: all 32 packed words fresh (no 0xFFFF half) ----
    for (;;) {
      asm volatile("s_waitcnt vmcnt(0)" ::: "memory");
      __builtin_amdgcn_sched_barrier(0);
      bool ok = fresh4_(q0) && fresh4_(q1) && fresh4_(q2) && fresh4_(q3)
             && fresh4_(q4) && fresh4_(q5) && fresh4_(q6) && fresh4_(q7);
      if (__all((int)ok)) break;
      __builtin_amdgcn_s_sleep(1);
      POLL8(pl, pl + 4096);
    }

    // ---- payloads ARE the A-fragments ----
    short8 a0 = __builtin_bit_cast(short8, q0), a1 = __builtin_bit_cast(short8, q1);
    short8 a2 = __builtin_bit_cast(short8, q2), a3 = __builtin_bit_cast(short8, q3);
    short8 a4 = __builtin_bit_cast(short8, q4), a5 = __builtin_bit_cast(short8, q5);
    short8 a6 = __builtin_bit_cast(short8, q6), a7 = __builtin_bit_cast(short8, q7);

    // ---- MFMA: 2 gates x (16x16, K=256) ----
    f32x4 acc0 = (f32x4){0.f, 0.f, 0.f, 0.f};
    f32x4 acc1 = (f32x4){0.f, 0.f, 0.f, 0.f};
    acc0 = __builtin_amdgcn_mfma_f32_16x16x32_bf16(a0, wfrag[0][0], acc0, 0, 0, 0);
    acc1 = __builtin_amdgcn_mfma_f32_16x16x32_bf16(a0, wfrag[1][0], acc1, 0, 0, 0);
    acc0 = __builtin_amdgcn_mfma_f32_16x16x32_bf16(a1, wfrag[0][1], acc0, 0, 0, 0);
    acc1 = __builtin_amdgcn_mfma_f32_16x16x32_bf16(a1, wfrag[1][1], acc1, 0, 0, 0);
    acc0 = __builtin_amdgcn_mfma_f32_16x16x32_bf16(a2, wfrag[0][2], acc0, 0, 0, 0);
    acc1 = __builtin_amdgcn_mfma_f32_16x16x32_bf16(a2, wfrag[1][2], acc1, 0, 0, 0);
    acc0 = __builtin_amdgcn_mfma_f32_16x16x32_bf16(a3, wfrag[0][3], acc0, 0, 0, 0);
    acc1 = __builtin_amdgcn_mfma_f32_16x16x32_bf16(a3, wfrag[1][3], acc1, 0, 0, 0);
    acc0 = __builtin_amdgcn_mfma_f32_16x16x32_bf16(a4, wfrag[0][4], acc0, 0, 0, 0);
    acc1 = __builtin_amdgcn_mfma_f32_16x16x32_bf16(a4, wfrag[1][4], acc1, 0, 0, 0);
    acc0 = __builtin_amdgcn_mfma_f32_16x16x32_bf16(a5, wfrag[0][5], acc0, 0, 0, 0);
    acc1 = __builtin_amdgcn_mfma_f32_16x16x32_bf16(a5, wfrag[1][5], acc1, 0, 0, 0);
    acc0 = __builtin_amdgcn_mfma_f32_16x16x32_bf16(a6, wfrag[0][6], acc0, 0, 0, 0);
    acc1 = __builtin_amdgcn_mfma_f32_16x16x32_bf16(a6, wfrag[1][6], acc1, 0, 0, 0);
    acc0 = __builtin_amdgcn_mfma_f32_16x16x32_bf16(a7, wfrag[0][7], acc0, 0, 0, 0);
    acc1 = __builtin_amdgcn_mfma_f32_16x16x32_bf16(a7, wfrag[1][7], acc1, 0, 0, 0);

    // C-frag: col(j)=r16, row(b)=kgrp*4+i -> b128 store into parity z_s
    *(f32x4*)&z_s[par][ks][2 * gp + 0][r16][kgrp * 4] = acc0;
    *(f32x4*)&z_s[par][ks][2 * gp + 1][r16][kgrp * 4] = acc1;
    __syncthreads();   // B1: the ONLY barrier per step

    if (gt) {
      // ---- gates (thread = (b, jj)): sum the 4 K-quarter partials ----
      float zq[4];
      #pragma unroll
      for (int g = 0; g < 4; ++g)
        zq[g] = ((z_s[par][0][g][jj][b] + z_s[par][1][g][jj][b]) +
                 (z_s[par][2][g][jj][b] + z_s[par][3][g][jj][b])) + bf2f(ipr[g]);
      const float cell = tanhf_(zq[0]);
      const float ig = sigmoidf_(zq[1]);
      const float fg = sigmoidf_(zq[2]);
      const float og = sigmoidf_(zq[3]);
      const float cn = fg * creg + ig * cell;
      const float yn = og * tanhf_(cn);
      const float cnew = mreg * cn + (1.0f - mreg) * creg;
      const float ynew = mreg * yn;
      creg = cnew;

      // ---- publish h(t+1) into the FRESH buffer t+1 (fragment-linear layout) ----
      if (t < T_STEPS - 1) {
        const unsigned short yb = f2bf(ynew);
        const unsigned prt = (unsigned)(unsigned short)__shfl_xor((int)(unsigned)yb, 1);
        if ((tid & 1) == 0) {
          unsigned* dst = hseq + (size_t)(t + 1) * PWORDS;
          __hip_atomic_store(&dst[pubw], ((unsigned)yb) | (prt << 16),
                             __ATOMIC_RELAXED, __HIP_MEMORY_SCOPE_AGENT);
        }
      }
      // outputs (nontemporal) + next-step operand prefetch
      const size_t ob = ((size_t)t * BATCH + b) * NH_D + j0 + jj;
      __builtin_nontemporal_store(ynew, &Y[ob]);
      __builtin_nontemporal_store(cnew, &C[ob]);
      if (t < T_STEPS - 1) {
        const unsigned short* ipn = intern + ((size_t)(t + 1) * BATCH + b) * G_D;
        #pragma unroll
        for (int g = 0; g < 4; ++g)
          ipr[g] = ipn[g * NH_D + j0 + jj];
        mreg = msk[(t + 1) * BATCH + b];
      }
    }

    // issue next step's polls last (non-gate waves: right after B1, overlapping gates)
    if (t < T_STEPS - 1) {
      const char* pn = (const char*)(hseq + (size_t)(t + 1) * PWORDS) + pboff;
      POLL8(pn, pn + 4096);
    }
  }
  if (gt) D[b * NH_D + j0 + jj] = creg;
}

extern "C" void kernel_launch(void* const* d_in, const int* in_sizes, int n_in,
                              void* d_out, int out_size, void* d_ws, size_t ws_size,
                              hipStream_t stream) {
  const float* X     = (const float*)d_in[0];
  const float* imask = (const float*)d_in[1];
  const float* h0    = (const float*)d_in[2];
  const float* c0    = (const float*)d_in[3];
  const float* Win   = (const float*)d_in[4];
  const float* Wre   = (const float*)d_in[5];
  const float* bias  = (const float*)d_in[6];
  float* out = (float*)d_out;

  char* ws = (char*)d_ws;
  unsigned short* Xbf    = (unsigned short*)(ws);                         // 64 MB (dead after gemm)
  unsigned short* WinT   = (unsigned short*)(ws + 67108864);              // 8 MB
  unsigned short* WreT   = (unsigned short*)(ws + 75497472);              // 8 MB
  unsigned short* intern = (unsigned short*)(ws + 83886080);              // 256 MB
  unsigned*       hseq   = (unsigned*)(ws);                               // 64 MB = 2048 x 32 KB, overlays Xbf

  float* Y = out;
  float* C = out + (size_t)T_STEPS * BATCH * NH_D;
  float* D = out + (size_t)2 * T_STEPS * BATCH * NH_D;

  {
    int n4 = (MROWS * NIN_D) / 4;
    cast_f32_bf16<<<dim3((n4 + 255) / 256), dim3(256), 0, stream>>>(X, Xbf, n4);
  }
  transpose_cast<<<dim3(G_D / 32, NIN_D / 32), dim3(32, 8), 0, stream>>>(Win, WinT);
  transpose_cast<<<dim3(G_D / 32, NH_D / 32),  dim3(32, 8), 0, stream>>>(Wre, WreT);

  gemm_intern<<<dim3(G_D / 128, MROWS / 128), dim3(256), 0, stream>>>(Xbf, WinT, bias, intern);

  // hseq overlays the (now dead) Xbf region; fill buf0 = h0, rest = empty, every launch
  init_hseq<<<dim3(1024), dim3(256), 0, stream>>>(h0, (u32x4*)hseq);

  lstm_scan<<<dim3(NWG), dim3(WGT), 0, stream>>>(intern, WreT, imask, c0, hseq, Y, C, D);
}

// Round 12
// 6230.074 us; speedup vs baseline: 1.6109x; 1.1425x over previous
//
#include <hip/hip_runtime.h>
#include <cstdint>
#include <cstddef>

#define T_STEPS 2048
#define BATCH   16
#define NIN_D   1024
#define NH_D    1024
#define G_D     4096
#define MROWS   32768   // T*B
#define NWG     64      // scan workgroups
#define WGT     512     // threads per scan wg (8 waves)
#define PWORDS  8192    // packed u32 words per step buffer (2 bf16 each = 32 KB)

typedef short short8 __attribute__((ext_vector_type(8)));
typedef float f32x4  __attribute__((ext_vector_type(4)));
typedef unsigned u32x4 __attribute__((ext_vector_type(4)));

__device__ __forceinline__ unsigned short f2bf(float f) {
  unsigned u = __builtin_bit_cast(unsigned, f);
  u += 0x7FFFu + ((u >> 16) & 1u);          // RNE
  return (unsigned short)(u >> 16);
}
__device__ __forceinline__ float bf2f(unsigned short h) {
  unsigned u = ((unsigned)h) << 16;
  return __builtin_bit_cast(float, u);
}
__device__ __forceinline__ float sigmoidf_(float x) { return 1.0f / (1.0f + __expf(-x)); }
__device__ __forceinline__ float tanhf_(float x)    { return 2.0f / (1.0f + __expf(-2.0f * x)) - 1.0f; }

// ---------------- cast X: f32 -> bf16, vectorized ----------------
__global__ void cast_f32_bf16(const float* __restrict__ in, unsigned short* __restrict__ out, int n4) {
  int idx = blockIdx.x * blockDim.x + threadIdx.x;
  if (idx < n4) {
    float4 v = ((const float4*)in)[idx];
    ushort4 o;
    o.x = f2bf(v.x); o.y = f2bf(v.y); o.z = f2bf(v.z); o.w = f2bf(v.w);
    ((ushort4*)out)[idx] = o;
  }
}

// ---------------- transpose+cast W [1024][4096] f32 -> WT [4096][1024] bf16 ----------------
__global__ void transpose_cast(const float* __restrict__ in, unsigned short* __restrict__ out) {
  __shared__ float tile[32][33];
  const int gx = blockIdx.x * 32;
  const int gy = blockIdx.y * 32;
  const int tx = threadIdx.x, ty = threadIdx.y;   // (32,8)
  #pragma unroll
  for (int p = 0; p < 4; ++p)
    tile[ty + p * 8][tx] = in[(size_t)(gy + ty + p * 8) * G_D + gx + tx];
  __syncthreads();
  #pragma unroll
  for (int p = 0; p < 4; ++p)
    out[(size_t)(gx + ty + p * 8) * NIN_D + gy + tx] = f2bf(tile[tx][ty + p * 8]);
}

// ---------------- init h sequence (WG-MAJOR publish layout) ----------------
// word w: wg = w>>7, b = (w>>3)&15, q = w&7 -> h element pair j = wg*16 + 2q, +1.
// Each wg's publish region is one contiguous 512B block.
// buf0 = packed bf16(h0); bufs 1..2047 = 0xFFFFFFFF (empty; f2bf of |y|<=1 never
// yields 0xFFFF). Runs every launch (graph-replay safe).
__global__ void init_hseq(const float* __restrict__ h0, u32x4* __restrict__ hs) {
  const int nq = (T_STEPS * PWORDS) / 4;   // 4,194,304 quads (64 MB)
  for (int q4 = blockIdx.x * blockDim.x + threadIdx.x; q4 < nq; q4 += gridDim.x * blockDim.x) {
    u32x4 v;
    if (q4 < PWORDS / 4) {
      const int w0 = q4 * 4;
      const int wg = w0 >> 7, b = (w0 >> 3) & 15, q0 = w0 & 7;
      const float* hb = h0 + b * NH_D + wg * 16 + q0 * 2;
      #pragma unroll
      for (int u = 0; u < 4; ++u) {
        unsigned lo = f2bf(hb[2 * u]);
        unsigned hi = f2bf(hb[2 * u + 1]);
        lo = (lo == 0xFFFFu) ? 0xFFFEu : lo;     // robustness: never poison
        hi = (hi == 0xFFFFu) ? 0xFFFEu : hi;
        v[u] = lo | (hi << 16);
      }
    } else {
      v = (u32x4){0xFFFFFFFFu, 0xFFFFFFFFu, 0xFFFFFFFFu, 0xFFFFFFFFu};
    }
    hs[q4] = v;
  }
}

// ---------------- intern GEMM: C[m][g] = A[m][:] . BT[g][:] + bias[g] (bf16 out) ----------------
__global__ __launch_bounds__(256) void gemm_intern(
    const unsigned short* __restrict__ A,
    const unsigned short* __restrict__ Bt,
    const float* __restrict__ bias,
    unsigned short* __restrict__ Out) {
  __shared__ unsigned short As[128 * 72];
  __shared__ unsigned short Bs[128 * 72];
  const int tid  = threadIdx.x;
  const int lane = tid & 63;
  const int w    = tid >> 6;
  const int r16  = lane & 15;
  const int kgrp = lane >> 4;
  const int wrow = (w >> 1) * 64;
  const int wcol = (w & 1) * 64;
  const int bx = blockIdx.x;
  const int by = blockIdx.y;

  const unsigned short* Ag = A  + (size_t)by * 128 * NIN_D;
  const unsigned short* Bg = Bt + (size_t)bx * 128 * NIN_D;
  const int trow = tid >> 3;
  const int tcol = (tid & 7) * 8;

  f32x4 acc[4][4];
  #pragma unroll
  for (int m = 0; m < 4; ++m)
    #pragma unroll
    for (int n = 0; n < 4; ++n)
      acc[m][n] = (f32x4){0.f, 0.f, 0.f, 0.f};

  for (int kt = 0; kt < 16; ++kt) {
    const int kb = kt * 64;
    __syncthreads();
    #pragma unroll
    for (int p = 0; p < 4; ++p) {
      const int r = trow + p * 32;
      *(uint4*)(&As[r * 72 + tcol]) = *(const uint4*)(Ag + (size_t)r * NIN_D + kb + tcol);
      *(uint4*)(&Bs[r * 72 + tcol]) = *(const uint4*)(Bg + (size_t)r * NIN_D + kb + tcol);
    }
    __syncthreads();
    #pragma unroll
    for (int kk = 0; kk < 2; ++kk) {
      const int ko = kk * 32 + kgrp * 8;
      short8 af[4], bq[4];
      #pragma unroll
      for (int m = 0; m < 4; ++m)
        af[m] = *(const short8*)(&As[(wrow + m * 16 + r16) * 72 + ko]);
      #pragma unroll
      for (int n = 0; n < 4; ++n)
        bq[n] = *(const short8*)(&Bs[(wcol + n * 16 + r16) * 72 + ko]);
      #pragma unroll
      for (int m = 0; m < 4; ++m)
        #pragma unroll
        for (int n = 0; n < 4; ++n)
          acc[m][n] = __builtin_amdgcn_mfma_f32_16x16x32_bf16(af[m], bq[n], acc[m][n], 0, 0, 0);
    }
  }
  #pragma unroll
  for (int n = 0; n < 4; ++n) {
    const int col = bx * 128 + wcol + n * 16 + r16;
    const float bv = bias[col];
    #pragma unroll
    for (int m = 0; m < 4; ++m) {
      const int row0 = by * 128 + wrow + m * 16 + kgrp * 4;
      #pragma unroll
      for (int i = 0; i < 4; ++i)
        Out[(size_t)(row0 + i) * G_D + col] = f2bf(acc[m][n][i] + bv);
    }
  }
}

// issue this lane's 4 dwordx4 loads of its wave's 4KB slice (4 x contiguous 1KB)
#define POLL4(P) asm volatile( \
    "global_load_dwordx4 %0, %4, off sc0 sc1\n\t" \
    "global_load_dwordx4 %1, %4, off offset:1024 sc0 sc1\n\t" \
    "global_load_dwordx4 %2, %4, off offset:2048 sc0 sc1\n\t" \
    "global_load_dwordx4 %3, %4, off offset:3072 sc0 sc1" \
    : "=v"(a0), "=v"(a1), "=v"(a2), "=v"(a3) \
    : "v"(P) : "memory")

__device__ __forceinline__ bool fresh4_(u32x4 v) {
  bool ok = true;
  #pragma unroll
  for (int u = 0; u < 4; ++u)
    ok = ok && ((v[u] & 0xFFFFu) != 0xFFFFu) && ((v[u] >> 16) != 0xFFFFu);
  return ok;
}

// ---------------- persistent LSTM scan ----------------
// 64 wgs x 512 threads (8 waves). wg owns 16 hidden units = 64 gate cols.
// Wave wv = K-EIGHTH (128 k-values): polls exactly the contiguous 4KB slice it
// MFMA-reads (zero redundancy; accepting load == payload), stages WAVE-LOCALLY
// into its own LDS tile (ds ordering, no barrier), computes all 4 gates over
// K=128 (16 MFMA), writes partial z. ONE __syncthreads per step. Fresh buffer
// per step (no reuse -> no WAR reasoning). WG-major publish = contiguous 512B.
__global__ __launch_bounds__(WGT, 2) void lstm_scan(
    const unsigned short* __restrict__ intern, // [32768][4096] bf16
    const unsigned short* __restrict__ WreT,   // [4096][1024] bf16
    const float* __restrict__ msk,             // [2048][16]
    const float* __restrict__ c0,              // [16][1024]
    unsigned* __restrict__ hseq,               // [2048][PWORDS] wg-major packed
    float* __restrict__ Y, float* __restrict__ C, float* __restrict__ D) {
  const int wg = blockIdx.x;
  const int tid = threadIdx.x;
  const int wv = tid >> 6, lane = tid & 63;
  const int r16 = lane & 15, kgrp = lane >> 4;
  const int j0 = wg * 16;

  __shared__ __attribute__((aligned(16))) unsigned short h_w[8][16][132]; // per-wave k-eighth tile
  __shared__ __attribute__((aligned(16))) float z_s[8][4][16][20];        // [ke][gate][j][b+pad]

  // ---- W_re B-fragments: 4 gates x 4 k-chunks over this wave's K-eighth (64 VGPR) ----
  short8 wfrag[4][4];
  #pragma unroll
  for (int g = 0; g < 4; ++g) {
    const unsigned short* wp =
        WreT + (size_t)(g * NH_D + j0 + r16) * NH_D + wv * 128 + kgrp * 8;
    #pragma unroll
    for (int kc = 0; kc < 4; ++kc)
      wfrag[g][kc] = *(const short8*)(wp + kc * 32);
  }

  // ---- gate-thread mapping: tid<256 (waves 0..3) -> (b = tid>>4, jj = tid&15) ----
  const int b = tid >> 4, jj = tid & 15;
  const bool gt = tid < 256;
  float creg = 0.f, mreg = 0.f;
  unsigned short ipr[4] = {0, 0, 0, 0};
  if (gt) {
    creg = c0[b * NH_D + j0 + jj];
    mreg = msk[b];
    #pragma unroll
    for (int g = 0; g < 4; ++g)
      ipr[g] = intern[(size_t)b * G_D + g * NH_D + j0 + jj];
  }

  // per-lane poll base (bytes): wave slice [wv*4096 .. +4096), lane covers 16B x 4 @ 1KB stride
  const int pboff = wv * 4096 + lane * 16;
  // stage mapping for load i: row b_ = (lane>>1)&15, col jl = i*32 + (lane>>5)*16 + (lane&1)*8
  const int stg_b = (lane >> 1) & 15;
  const int stg_j = ((lane >> 5) << 4) + ((lane & 1) << 3);
  // publish word (pair writer): wg*128 + b*8 + (jj>>1)
  const int pubw = (wg << 7) | (b << 3) | (jj >> 1);

  u32x4 a0, a1, a2, a3;
  POLL4((const char*)hseq + pboff);   // buffer 0 (pre-published by init_hseq)

  for (int t = 0; t < T_STEPS; ++t) {
    const char* pl = (const char*)(hseq + (size_t)t * PWORDS) + pboff;

    // ---- wait + accept: this wave's 4KB slice fully fresh ----
    for (;;) {
      asm volatile("s_waitcnt vmcnt(0)" ::: "memory");
      __builtin_amdgcn_sched_barrier(0);
      bool ok = fresh4_(a0) && fresh4_(a1) && fresh4_(a2) && fresh4_(a3);
      if (__all((int)ok)) break;
      __builtin_amdgcn_s_sleep(1);
      POLL4(pl);
    }

    // ---- wave-local stage into own tile (no barrier needed before own reads) ----
    *(u32x4*)&h_w[wv][stg_b][stg_j]      = a0;
    *(u32x4*)&h_w[wv][stg_b][stg_j + 32] = a1;
    *(u32x4*)&h_w[wv][stg_b][stg_j + 64] = a2;
    *(u32x4*)&h_w[wv][stg_b][stg_j + 96] = a3;

    // ---- A-fragments from own tile (lgkmcnt orders ds_write -> ds_read in-wave) ----
    short8 af[4];
    #pragma unroll
    for (int kc = 0; kc < 4; ++kc)
      af[kc] = *(const short8*)(&h_w[wv][r16][kc * 32 + kgrp * 8]);

    // ---- MFMA: 4 gates x (16x16, K=128) ----
    f32x4 acc[4];
    #pragma unroll
    for (int g = 0; g < 4; ++g) acc[g] = (f32x4){0.f, 0.f, 0.f, 0.f};
    #pragma unroll
    for (int kc = 0; kc < 4; ++kc)
      #pragma unroll
      for (int g = 0; g < 4; ++g)
        acc[g] = __builtin_amdgcn_mfma_f32_16x16x32_bf16(af[kc], wfrag[g][kc], acc[g], 0, 0, 0);

    // C-frag: col(j)=r16, row(b)=kgrp*4+i -> b128 store of partial z
    #pragma unroll
    for (int g = 0; g < 4; ++g)
      *(f32x4*)&z_s[wv][g][r16][kgrp * 4] = acc[g];
    __syncthreads();   // the ONLY barrier per step: all partial z visible

    if (gt) {
      // ---- gates (thread = (b, jj)): sum the 8 K-eighth partials ----
      float zq[4];
      #pragma unroll
      for (int g = 0; g < 4; ++g) {
        float s0 = (z_s[0][g][jj][b] + z_s[1][g][jj][b]) + (z_s[2][g][jj][b] + z_s[3][g][jj][b]);
        float s1 = (z_s[4][g][jj][b] + z_s[5][g][jj][b]) + (z_s[6][g][jj][b] + z_s[7][g][jj][b]);
        zq[g] = s0 + s1 + bf2f(ipr[g]);
      }
      const float cell = tanhf_(zq[0]);
      const float ig = sigmoidf_(zq[1]);
      const float fg = sigmoidf_(zq[2]);
      const float og = sigmoidf_(zq[3]);
      const float cn = fg * creg + ig * cell;
      const float yn = og * tanhf_(cn);
      const float cnew = mreg * cn + (1.0f - mreg) * creg;
      const float ynew = mreg * yn;
      creg = cnew;

      // ---- publish h(t+1): contiguous 512B per wg, fire-and-forget ----
      if (t < T_STEPS - 1) {
        const unsigned short yb = f2bf(ynew);
        const unsigned prt = (unsigned)(unsigned short)__shfl_xor((int)(unsigned)yb, 1);
        if ((tid & 1) == 0) {
          unsigned* dst = hseq + (size_t)(t + 1) * PWORDS;
          __hip_atomic_store(&dst[pubw], ((unsigned)yb) | (prt << 16),
                             __ATOMIC_RELAXED, __HIP_MEMORY_SCOPE_AGENT);
        }
      }
      // outputs (nontemporal) + next-step operand prefetch
      const size_t ob = ((size_t)t * BATCH + b) * NH_D + j0 + jj;
      __builtin_nontemporal_store(ynew, &Y[ob]);
      __builtin_nontemporal_store(cnew, &C[ob]);
      if (t < T_STEPS - 1) {
        const unsigned short* ipn = intern + ((size_t)(t + 1) * BATCH + b) * G_D;
        #pragma unroll
        for (int g = 0; g < 4; ++g)
          ipr[g] = ipn[g * NH_D + j0 + jj];
        mreg = msk[(t + 1) * BATCH + b];
      }
    }

    // issue next step's polls (non-gate waves: right after the barrier -> overlaps gates)
    if (t < T_STEPS - 1)
      POLL4((const char*)(hseq + (size_t)(t + 1) * PWORDS) + pboff);
  }
  if (gt) D[b * NH_D + j0 + jj] = creg;
}

extern "C" void kernel_launch(void* const* d_in, const int* in_sizes, int n_in,
                              void* d_out, int out_size, void* d_ws, size_t ws_size,
                              hipStream_t stream) {
  const float* X     = (const float*)d_in[0];
  const float* imask = (const float*)d_in[1];
  const float* h0    = (const float*)d_in[2];
  const float* c0    = (const float*)d_in[3];
  const float* Win   = (const float*)d_in[4];
  const float* Wre   = (const float*)d_in[5];
  const float* bias  = (const float*)d_in[6];
  float* out = (float*)d_out;

  char* ws = (char*)d_ws;
  unsigned short* Xbf    = (unsigned short*)(ws);                         // 64 MB (dead after gemm)
  unsigned short* WinT   = (unsigned short*)(ws + 67108864);              // 8 MB
  unsigned short* WreT   = (unsigned short*)(ws + 75497472);              // 8 MB
  unsigned short* intern = (unsigned short*)(ws + 83886080);              // 256 MB
  unsigned*       hseq   = (unsigned*)(ws);                               // 64 MB = 2048 x 32 KB, overlays Xbf

  float* Y = out;
  float* C = out + (size_t)T_STEPS * BATCH * NH_D;
  float* D = out + (size_t)2 * T_STEPS * BATCH * NH_D;

  {
    int n4 = (MROWS * NIN_D) / 4;
    cast_f32_bf16<<<dim3((n4 + 255) / 256), dim3(256), 0, stream>>>(X, Xbf, n4);
  }
  transpose_cast<<<dim3(G_D / 32, NIN_D / 32), dim3(32, 8), 0, stream>>>(Win, WinT);
  transpose_cast<<<dim3(G_D / 32, NH_D / 32),  dim3(32, 8), 0, stream>>>(Wre, WreT);

  gemm_intern<<<dim3(G_D / 128, MROWS / 128), dim3(256), 0, stream>>>(Xbf, WinT, bias, intern);

  // hseq overlays the (now dead) Xbf region; fill buf0 = h0, rest = empty, every launch
  init_hseq<<<dim3(1024), dim3(256), 0, stream>>>(h0, (u32x4*)hseq);

  lstm_scan<<<dim3(NWG), dim3(WGT), 0, stream>>>(intern, WreT, imask, c0, hseq, Y, C, D);
}

// Round 15
// 6129.208 us; speedup vs baseline: 1.6374x; 1.0165x over previous
//
#include <hip/hip_runtime.h>
#include <cstdint>
#include <cstddef>

#define T_STEPS 2048
#define BATCH   16
#define NIN_D   1024
#define NH_D    1024
#define G_D     4096
#define MROWS   32768   // T*B
#define NWG     64      // scan workgroups
#define WGT     512     // threads per scan wg (8 waves)
#define PWORDS  8192    // packed u32 words per step buffer (2 bf16 each = 32 KB)

typedef short short8 __attribute__((ext_vector_type(8)));
typedef float f32x4  __attribute__((ext_vector_type(4)));
typedef unsigned u32x4 __attribute__((ext_vector_type(4)));

__device__ __forceinline__ unsigned short f2bf(float f) {
  unsigned u = __builtin_bit_cast(unsigned, f);
  u += 0x7FFFu + ((u >> 16) & 1u);          // RNE
  return (unsigned short)(u >> 16);
}
__device__ __forceinline__ float bf2f(unsigned short h) {
  unsigned u = ((unsigned)h) << 16;
  return __builtin_bit_cast(float, u);
}
__device__ __forceinline__ float sigmoidf_(float x) { return 1.0f / (1.0f + __expf(-x)); }
__device__ __forceinline__ float tanhf_(float x)    { return 2.0f / (1.0f + __expf(-2.0f * x)) - 1.0f; }

// ---------------- cast X: f32 -> bf16, vectorized ----------------
__global__ void cast_f32_bf16(const float* __restrict__ in, unsigned short* __restrict__ out, int n4) {
  int idx = blockIdx.x * blockDim.x + threadIdx.x;
  if (idx < n4) {
    float4 v = ((const float4*)in)[idx];
    ushort4 o;
    o.x = f2bf(v.x); o.y = f2bf(v.y); o.z = f2bf(v.z); o.w = f2bf(v.w);
    ((ushort4*)out)[idx] = o;
  }
}

// ---------------- transpose+cast W [1024][4096] f32 -> WT [4096][1024] bf16 ----------------
__global__ void transpose_cast(const float* __restrict__ in, unsigned short* __restrict__ out) {
  __shared__ float tile[32][33];
  const int gx = blockIdx.x * 32;
  const int gy = blockIdx.y * 32;
  const int tx = threadIdx.x, ty = threadIdx.y;   // (32,8)
  #pragma unroll
  for (int p = 0; p < 4; ++p)
    tile[ty + p * 8][tx] = in[(size_t)(gy + ty + p * 8) * G_D + gx + tx];
  __syncthreads();
  #pragma unroll
  for (int p = 0; p < 4; ++p)
    out[(size_t)(gx + ty + p * 8) * NIN_D + gy + tx] = f2bf(tile[tx][ty + p * 8]);
}

// ---------------- init h sequence (WG-MAJOR publish layout) ----------------
// word w: wg = w>>7, b = (w>>3)&15, q = w&7 -> h element pair j = wg*16 + 2q, +1.
// buf0 = packed bf16(h0); bufs 1..2047 = 0xFFFFFFFF (empty; f2bf of |y|<=1 never
// yields 0xFFFF). Runs every launch (graph-replay safe).
__global__ void init_hseq(const float* __restrict__ h0, u32x4* __restrict__ hs) {
  const int nq = (T_STEPS * PWORDS) / 4;   // 4,194,304 quads (64 MB)
  for (int q4 = blockIdx.x * blockDim.x + threadIdx.x; q4 < nq; q4 += gridDim.x * blockDim.x) {
    u32x4 v;
    if (q4 < PWORDS / 4) {
      const int w0 = q4 * 4;
      const int wg = w0 >> 7, b = (w0 >> 3) & 15, q0 = w0 & 7;
      const float* hb = h0 + b * NH_D + wg * 16 + q0 * 2;
      #pragma unroll
      for (int u = 0; u < 4; ++u) {
        unsigned lo = f2bf(hb[2 * u]);
        unsigned hi = f2bf(hb[2 * u + 1]);
        lo = (lo == 0xFFFFu) ? 0xFFFEu : lo;     // robustness: never poison
        hi = (hi == 0xFFFFu) ? 0xFFFEu : hi;
        v[u] = lo | (hi << 16);
      }
    } else {
      v = (u32x4){0xFFFFFFFFu, 0xFFFFFFFFu, 0xFFFFFFFFu, 0xFFFFFFFFu};
    }
    hs[q4] = v;
  }
}

// ---------------- intern GEMM: C[m][g] = A[m][:] . BT[g][:] + bias[g] (bf16 out) ----------------
__global__ __launch_bounds__(256) void gemm_intern(
    const unsigned short* __restrict__ A,
    const unsigned short* __restrict__ Bt,
    const float* __restrict__ bias,
    unsigned short* __restrict__ Out) {
  __shared__ unsigned short As[128 * 72];
  __shared__ unsigned short Bs[128 * 72];
  const int tid  = threadIdx.x;
  const int lane = tid & 63;
  const int w    = tid >> 6;
  const int r16  = lane & 15;
  const int kgrp = lane >> 4;
  const int wrow = (w >> 1) * 64;
  const int wcol = (w & 1) * 64;
  const int bx = blockIdx.x;
  const int by = blockIdx.y;

  const unsigned short* Ag = A  + (size_t)by * 128 * NIN_D;
  const unsigned short* Bg = Bt + (size_t)bx * 128 * NIN_D;
  const int trow = tid >> 3;
  const int tcol = (tid & 7) * 8;

  f32x4 acc[4][4];
  #pragma unroll
  for (int m = 0; m < 4; ++m)
    #pragma unroll
    for (int n = 0; n < 4; ++n)
      acc[m][n] = (f32x4){0.f, 0.f, 0.f, 0.f};

  for (int kt = 0; kt < 16; ++kt) {
    const int kb = kt * 64;
    __syncthreads();
    #pragma unroll
    for (int p = 0; p < 4; ++p) {
      const int r = trow + p * 32;
      *(uint4*)(&As[r * 72 + tcol]) = *(const uint4*)(Ag + (size_t)r * NIN_D + kb + tcol);
      *(uint4*)(&Bs[r * 72 + tcol]) = *(const uint4*)(Bg + (size_t)r * NIN_D + kb + tcol);
    }
    __syncthreads();
    #pragma unroll
    for (int kk = 0; kk < 2; ++kk) {
      const int ko = kk * 32 + kgrp * 8;
      short8 af[4], bq[4];
      #pragma unroll
      for (int m = 0; m < 4; ++m)
        af[m] = *(const short8*)(&As[(wrow + m * 16 + r16) * 72 + ko]);
      #pragma unroll
      for (int n = 0; n < 4; ++n)
        bq[n] = *(const short8*)(&Bs[(wcol + n * 16 + r16) * 72 + ko]);
      #pragma unroll
      for (int m = 0; m < 4; ++m)
        #pragma unroll
        for (int n = 0; n < 4; ++n)
          acc[m][n] = __builtin_amdgcn_mfma_f32_16x16x32_bf16(af[m], bq[n], acc[m][n], 0, 0, 0);
    }
  }
  #pragma unroll
  for (int n = 0; n < 4; ++n) {
    const int col = bx * 128 + wcol + n * 16 + r16;
    const float bv = bias[col];
    #pragma unroll
    for (int m = 0; m < 4; ++m) {
      const int row0 = by * 128 + wrow + m * 16 + kgrp * 4;
      #pragma unroll
      for (int i = 0; i < 4; ++i)
        Out[(size_t)(row0 + i) * G_D + col] = f2bf(acc[m][n][i] + bv);
    }
  }
}

// issue this lane's 4 dwordx4 loads of its wave's 4KB slice (4 x contiguous 1KB)
#define POLL4(P) asm volatile( \
    "global_load_dwordx4 %0, %4, off sc0 sc1\n\t" \
    "global_load_dwordx4 %1, %4, off offset:1024 sc0 sc1\n\t" \
    "global_load_dwordx4 %2, %4, off offset:2048 sc0 sc1\n\t" \
    "global_load_dwordx4 %3, %4, off offset:3072 sc0 sc1" \
    : "=v"(a0), "=v"(a1), "=v"(a2), "=v"(a3) \
    : "v"(P) : "memory")

__device__ __forceinline__ bool fresh4_(u32x4 v) {
  bool ok = true;
  #pragma unroll
  for (int u = 0; u < 4; ++u)
    ok = ok && ((v[u] & 0xFFFFu) != 0xFFFFu) && ((v[u] >> 16) != 0xFFFFu);
  return ok;
}

// ---------------- persistent LSTM scan ----------------
// 64 wgs x 512 threads (8 waves). wg owns 16 hidden units = 64 gate cols.
// Wave wv = K-EIGHTH (128 k-values): polls exactly the contiguous 4KB slice it
// MFMA-reads (zero redundancy; accepting load == payload), stages WAVE-LOCALLY
// into its own LDS tile (in-wave lgkmcnt ordering, no barrier), computes all 4
// gates over K=128 (16 MFMA), writes partial z into PARITY-double-buffered z_s
// (closes the cross-step WAR window: same-parity reuse t->t+2 is ordered through
// every gate thread's read->publish chain across all 64 wgs). ONE __syncthreads
// per step. Fresh buffer per step -> no h-reuse reasoning. Next-step poll issued
// by ALL waves immediately after the barrier (flies during the gate phase).
__global__ __launch_bounds__(WGT, 2) void lstm_scan(
    const unsigned short* __restrict__ intern, // [32768][4096] bf16
    const unsigned short* __restrict__ WreT,   // [4096][1024] bf16
    const float* __restrict__ msk,             // [2048][16]
    const float* __restrict__ c0,              // [16][1024]
    unsigned* __restrict__ hseq,               // [2048][PWORDS] wg-major packed
    float* __restrict__ Y, float* __restrict__ C, float* __restrict__ D) {
  const int wg = blockIdx.x;
  const int tid = threadIdx.x;
  const int wv = tid >> 6, lane = tid & 63;
  const int r16 = lane & 15, kgrp = lane >> 4;
  const int j0 = wg * 16;

  __shared__ __attribute__((aligned(16))) unsigned short h_w[8][16][132]; // per-wave k-eighth tile
  __shared__ __attribute__((aligned(16))) float z_s[2][8][4][16][20];     // [par][ke][gate][j][b+pad]

  // ---- W_re B-fragments: 4 gates x 4 k-chunks over this wave's K-eighth (64 VGPR) ----
  short8 wfrag[4][4];
  #pragma unroll
  for (int g = 0; g < 4; ++g) {
    const unsigned short* wp =
        WreT + (size_t)(g * NH_D + j0 + r16) * NH_D + wv * 128 + kgrp * 8;
    #pragma unroll
    for (int kc = 0; kc < 4; ++kc)
      wfrag[g][kc] = *(const short8*)(wp + kc * 32);
  }

  // ---- gate-thread mapping: tid<256 (waves 0..3) -> (b = tid>>4, jj = tid&15) ----
  const int b = tid >> 4, jj = tid & 15;
  const bool gt = tid < 256;
  float creg = 0.f, mreg = 0.f;
  unsigned short ipr[4] = {0, 0, 0, 0};
  if (gt) {
    creg = c0[b * NH_D + j0 + jj];
    mreg = msk[b];
    #pragma unroll
    for (int g = 0; g < 4; ++g)
      ipr[g] = intern[(size_t)b * G_D + g * NH_D + j0 + jj];
  }

  // per-lane poll base (bytes): wave slice [wv*4096 .. +4096), lane covers 16B x 4 @ 1KB stride
  const int pboff = wv * 4096 + lane * 16;
  // stage mapping for load i: row b_ = (lane>>1)&15, col jl = i*32 + (lane>>5)*16 + (lane&1)*8
  const int stg_b = (lane >> 1) & 15;
  const int stg_j = ((lane >> 5) << 4) + ((lane & 1) << 3);
  // publish word (pair writer): wg*128 + b*8 + (jj>>1)
  const int pubw = (wg << 7) | (b << 3) | (jj >> 1);

  u32x4 a0, a1, a2, a3;
  POLL4((const char*)hseq + pboff);   // buffer 0 (pre-published by init_hseq)

  for (int t = 0; t < T_STEPS; ++t) {
    const int par = t & 1;
    const char* pl = (const char*)(hseq + (size_t)t * PWORDS) + pboff;

    // ---- wait + accept: this wave's 4KB slice fully fresh ----
    for (;;) {
      asm volatile("s_waitcnt vmcnt(0)" ::: "memory");
      __builtin_amdgcn_sched_barrier(0);
      bool ok = fresh4_(a0) && fresh4_(a1) && fresh4_(a2) && fresh4_(a3);
      if (__all((int)ok)) break;
      __builtin_amdgcn_s_sleep(1);
      POLL4(pl);
    }

    // ---- wave-local stage into own tile (no barrier needed before own reads) ----
    *(u32x4*)&h_w[wv][stg_b][stg_j]      = a0;
    *(u32x4*)&h_w[wv][stg_b][stg_j + 32] = a1;
    *(u32x4*)&h_w[wv][stg_b][stg_j + 64] = a2;
    *(u32x4*)&h_w[wv][stg_b][stg_j + 96] = a3;

    // ---- A-fragments from own tile (lgkmcnt orders ds_write -> ds_read in-wave) ----
    short8 af[4];
    #pragma unroll
    for (int kc = 0; kc < 4; ++kc)
      af[kc] = *(const short8*)(&h_w[wv][r16][kc * 32 + kgrp * 8]);

    // ---- MFMA: 4 gates x (16x16, K=128) ----
    f32x4 acc[4];
    #pragma unroll
    for (int g = 0; g < 4; ++g) acc[g] = (f32x4){0.f, 0.f, 0.f, 0.f};
    #pragma unroll
    for (int kc = 0; kc < 4; ++kc)
      #pragma unroll
      for (int g = 0; g < 4; ++g)
        acc[g] = __builtin_amdgcn_mfma_f32_16x16x32_bf16(af[kc], wfrag[g][kc], acc[g], 0, 0, 0);

    // C-frag: col(j)=r16, row(b)=kgrp*4+i -> b128 store of partial z (parity buffer)
    #pragma unroll
    for (int g = 0; g < 4; ++g)
      *(f32x4*)&z_s[par][wv][g][r16][kgrp * 4] = acc[g];
    __syncthreads();   // the ONLY barrier per step: all partial z visible

    // ---- next-step poll: ALL waves issue immediately (flies during gate phase).
    //      a0..a3 are dead here (consumed into h_w before the barrier) -> safe.
    const bool more = (t < T_STEPS - 1);
    if (more)
      POLL4((const char*)(hseq + (size_t)(t + 1) * PWORDS) + pboff);

    if (gt) {
      // ---- gates (thread = (b, jj)): sum the 8 K-eighth partials ----
      float zq[4];
      #pragma unroll
      for (int g = 0; g < 4; ++g) {
        float s0 = (z_s[par][0][g][jj][b] + z_s[par][1][g][jj][b]) +
                   (z_s[par][2][g][jj][b] + z_s[par][3][g][jj][b]);
        float s1 = (z_s[par][4][g][jj][b] + z_s[par][5][g][jj][b]) +
                   (z_s[par][6][g][jj][b] + z_s[par][7][g][jj][b]);
        zq[g] = s0 + s1 + bf2f(ipr[g]);
      }
      const float cell = tanhf_(zq[0]);
      const float ig = sigmoidf_(zq[1]);
      const float fg = sigmoidf_(zq[2]);
      const float og = sigmoidf_(zq[3]);
      const float cn = fg * creg + ig * cell;
      const float yn = og * tanhf_(cn);
      const float cnew = mreg * cn + (1.0f - mreg) * creg;
      const float ynew = mreg * yn;
      creg = cnew;

      // ---- publish h(t+1): contiguous 512B per wg, fire-and-forget ----
      if (more) {
        const unsigned short yb = f2bf(ynew);
        const unsigned prt = (unsigned)(unsigned short)__shfl_xor((int)(unsigned)yb, 1);
        if ((tid & 1) == 0) {
          unsigned* dst = hseq + (size_t)(t + 1) * PWORDS;
          __hip_atomic_store(&dst[pubw], ((unsigned)yb) | (prt << 16),
                             __ATOMIC_RELAXED, __HIP_MEMORY_SCOPE_AGENT);
        }
      }
      // outputs (nontemporal) + next-step operand prefetch
      const size_t ob = ((size_t)t * BATCH + b) * NH_D + j0 + jj;
      __builtin_nontemporal_store(ynew, &Y[ob]);
      __builtin_nontemporal_store(cnew, &C[ob]);
      if (more) {
        const unsigned short* ipn = intern + ((size_t)(t + 1) * BATCH + b) * G_D;
        #pragma unroll
        for (int g = 0; g < 4; ++g)
          ipr[g] = ipn[g * NH_D + j0 + jj];
        mreg = msk[(t + 1) * BATCH + b];
      }
    }
  }
  if (gt) D[b * NH_D + j0 + jj] = creg;
}

extern "C" void kernel_launch(void* const* d_in, const int* in_sizes, int n_in,
                              void* d_out, int out_size, void* d_ws, size_t ws_size,
                              hipStream_t stream) {
  const float* X     = (const float*)d_in[0];
  const float* imask = (const float*)d_in[1];
  const float* h0    = (const float*)d_in[2];
  const float* c0    = (const float*)d_in[3];
  const float* Win   = (const float*)d_in[4];
  const float* Wre   = (const float*)d_in[5];
  const float* bias  = (const float*)d_in[6];
  float* out = (float*)d_out;

  char* ws = (char*)d_ws;
  unsigned short* Xbf    = (unsigned short*)(ws);                         // 64 MB (dead after gemm)
  unsigned short* WinT   = (unsigned short*)(ws + 67108864);              // 8 MB
  unsigned short* WreT   = (unsigned short*)(ws + 75497472);              // 8 MB
  unsigned short* intern = (unsigned short*)(ws + 83886080);              // 256 MB
  unsigned*       hseq   = (unsigned*)(ws);                               // 64 MB = 2048 x 32 KB, overlays Xbf

  float* Y = out;
  float* C = out + (size_t)T_STEPS * BATCH * NH_D;
  float* D = out + (size_t)2 * T_STEPS * BATCH * NH_D;

  {
    int n4 = (MROWS * NIN_D) / 4;
    cast_f32_bf16<<<dim3((n4 + 255) / 256), dim3(256), 0, stream>>>(X, Xbf, n4);
  }
  transpose_cast<<<dim3(G_D / 32, NIN_D / 32), dim3(32, 8), 0, stream>>>(Win, WinT);
  transpose_cast<<<dim3(G_D / 32, NH_D / 32),  dim3(32, 8), 0, stream>>>(Wre, WreT);

  gemm_intern<<<dim3(G_D / 128, MROWS / 128), dim3(256), 0, stream>>>(Xbf, WinT, bias, intern);

  // hseq overlays the (now dead) Xbf region; fill buf0 = h0, rest = empty, every launch
  init_hseq<<<dim3(1024), dim3(256), 0, stream>>>(h0, (u32x4*)hseq);

  lstm_scan<<<dim3(NWG), dim3(WGT), 0, stream>>>(intern, WreT, imask, c0, hseq, Y, C, D);
}